// Round 1
// baseline (487.754 us; speedup 1.0000x reference)
//
#include <hip/hip_runtime.h>
#include <hip/hip_bf16.h>

// EvenOddFunctionHAM: out = rho(rho(s)@W + b_odd + [Ux|0]) @ W^T + b_even
// W is block-staircase: blocks (0,0),(0,1),(1,1) of 2048^2 nonzero.
// Strategy: bf16 MFMA GEMMs (m97 128^2-tile structure), fused activation
// epilogues, block-sparse K-ranges.
//
// Workspace layout (needs 128 MB):
//   [0,32M)    Rs  = bf16(rho(s))        [4096][4096]
//   [32M,64M)  R2  = bf16(rho(s_odd))    [4096][4096]
//   [64M,96M)  Wb  = bf16(W*mask)        [4096][4096]  (= B^T layout for GEMM2)
//   [96M,128M) WTb = bf16((W*mask)^T)    [4096][4096]  (= B^T layout for GEMM1)

#define N_DIM 4096
#define D1_DIM 2048

typedef short short8 __attribute__((ext_vector_type(8)));
typedef float f32x4 __attribute__((ext_vector_type(4)));

__device__ __forceinline__ float rho_f(float x) {
    // sigmoid(4x-2) = 1/(1+exp(2-4x))
    return 1.0f / (1.0f + __expf(2.0f - 4.0f * x));
}

__device__ __forceinline__ unsigned short f2bf(float x) {
    // round-to-nearest-even f32 -> bf16 (finite inputs only)
    unsigned int u = __builtin_bit_cast(unsigned int, x);
    u += 0x7fffu + ((u >> 16) & 1u);
    return (unsigned short)(u >> 16);
}

__device__ __forceinline__ void gl_lds16(const unsigned short* g, unsigned short* l) {
    // async global->LDS, 16B per lane; LDS dest = wave-uniform base + lane*16
    __builtin_amdgcn_global_load_lds(
        (const __attribute__((address_space(1))) void*)g,
        (__attribute__((address_space(3))) void*)l, 16, 0, 0);
}

// ---------------- prep: Rs = bf16(rho(s)) ----------------
__global__ void prep_rs_kernel(const float* __restrict__ s,
                               unsigned short* __restrict__ Rs, int n8) {
    int t = blockIdx.x * blockDim.x + threadIdx.x;
    int stride = gridDim.x * blockDim.x;
    for (int i = t; i < n8; i += stride) {
        float4 a = ((const float4*)s)[2 * i];
        float4 b = ((const float4*)s)[2 * i + 1];
        unsigned int r0 = f2bf(rho_f(a.x)) | ((unsigned int)f2bf(rho_f(a.y)) << 16);
        unsigned int r1 = f2bf(rho_f(a.z)) | ((unsigned int)f2bf(rho_f(a.w)) << 16);
        unsigned int r2 = f2bf(rho_f(b.x)) | ((unsigned int)f2bf(rho_f(b.y)) << 16);
        unsigned int r3 = f2bf(rho_f(b.z)) | ((unsigned int)f2bf(rho_f(b.w)) << 16);
        uint4 o; o.x = r0; o.y = r1; o.z = r2; o.w = r3;
        ((uint4*)Rs)[i] = o;
    }
}

// ---------------- prep: Wb = bf16(W*mask); WTb = transpose ----------------
__global__ void prep_w_kernel(const float* __restrict__ W,
                              const float* __restrict__ Wm,
                              unsigned short* __restrict__ Wb,
                              unsigned short* __restrict__ WTb) {
    __shared__ unsigned short t[32][33];  // +1 pad breaks bank-conflict on transpose read
    int x = blockIdx.x * 32 + threadIdx.x;
    #pragma unroll
    for (int r = 0; r < 4; r++) {
        int y = blockIdx.y * 32 + threadIdx.y + r * 8;
        size_t idx = (size_t)y * N_DIM + x;
        unsigned short b = f2bf(W[idx] * Wm[idx]);
        Wb[idx] = b;
        t[threadIdx.y + r * 8][threadIdx.x] = b;
    }
    __syncthreads();
    #pragma unroll
    for (int r = 0; r < 4; r++) {
        int yy = threadIdx.y + r * 8;
        int orow = blockIdx.x * 32 + yy;          // WT row = original col
        int ocol = blockIdx.y * 32 + threadIdx.x; // WT col = original row
        WTb[(size_t)orow * N_DIM + ocol] = t[threadIdx.x][yy];
    }
}

// ---------------- GEMM: C = A @ Bt^T  (A[M][K], Bt[N][K], bf16, fp32 acc) --
// 128x128 tile, BK=32, 4 waves (2x2), 4x4 16x16x32 fragments per wave.
// MODE 1: out = bf16(rho(acc + b_odd[col] + (col<D1 ? Ux : 0)))   (R2, bf16)
// MODE 2: out = acc + b_even[col]                                  (d_out, f32)
template<int MODE>
__global__ __launch_bounds__(256) void gemm_kernel(
    const unsigned short* __restrict__ A,
    const unsigned short* __restrict__ Bt,
    void* __restrict__ Out,
    const float* __restrict__ Ux,
    const float* __restrict__ bias) {
    __shared__ unsigned short As[128 * 32];
    __shared__ unsigned short Bs[128 * 32];
    const int brow = blockIdx.y * 128;
    const int bcol = blockIdx.x * 128;
    const int tid = threadIdx.x;
    const int wid = tid >> 6;
    const int lane = tid & 63;
    const int wr = wid >> 1, wc = wid & 1;

    // block-sparse K range (skipped region of Bt is all-zero anyway)
    int kbeg, kend;
    if (MODE == 1) { kbeg = 0; kend = (bcol < D1_DIM) ? D1_DIM : N_DIM; }
    else           { kbeg = (bcol < D1_DIM) ? 0 : D1_DIM; kend = N_DIM; }

    // staging: tile is 128 rows x 32 cols bf16 = 8 KB = 8 chunks of 1KB;
    // each wave stages 2 chunks of A and 2 of B. chunk c = rows [16c,16c+16).
    const int c0 = wid * 2;
    const int srow = c0 * 16 + (lane >> 2);
    const int scol = (lane & 3) << 3;
    const unsigned short* gA0 = A  + (size_t)(brow + srow) * N_DIM + scol + kbeg;
    const unsigned short* gA1 = gA0 + 16 * N_DIM;
    const unsigned short* gB0 = Bt + (size_t)(bcol + srow) * N_DIM + scol + kbeg;
    const unsigned short* gB1 = gB0 + 16 * N_DIM;
    unsigned short* lA0 = &As[c0 * 512];
    unsigned short* lA1 = lA0 + 512;
    unsigned short* lB0 = &Bs[c0 * 512];
    unsigned short* lB1 = lB0 + 512;

    f32x4 acc[4][4];
    #pragma unroll
    for (int m = 0; m < 4; m++)
        #pragma unroll
        for (int n = 0; n < 4; n++)
            acc[m][n] = (f32x4){0.f, 0.f, 0.f, 0.f};

    const int fr = lane & 15;
    const int fq = lane >> 4;
    const unsigned short* rA = &As[(wr * 64 + fr) * 32 + fq * 8];
    const unsigned short* rB = &Bs[(wc * 64 + fr) * 32 + fq * 8];

    const int nk = (kend - kbeg) >> 5;
    for (int t = 0; t < nk; t++) {
        const int ko = t << 5;
        gl_lds16(gA0 + ko, lA0);
        gl_lds16(gA1 + ko, lA1);
        gl_lds16(gB0 + ko, lB0);
        gl_lds16(gB1 + ko, lB1);
        asm volatile("s_waitcnt vmcnt(0)" ::: "memory");
        __syncthreads();
        short8 af[4], bq[4];
        #pragma unroll
        for (int m = 0; m < 4; m++)
            af[m] = *(const short8*)(rA + m * 16 * 32);
        #pragma unroll
        for (int n = 0; n < 4; n++)
            bq[n] = *(const short8*)(rB + n * 16 * 32);
        #pragma unroll
        for (int m = 0; m < 4; m++)
            #pragma unroll
            for (int n = 0; n < 4; n++)
                acc[m][n] = __builtin_amdgcn_mfma_f32_16x16x32_bf16(
                    af[m], bq[n], acc[m][n], 0, 0, 0);
        __syncthreads();
    }

    // epilogue: C/D layout col = lane&15, row = (lane>>4)*4 + reg
    #pragma unroll
    for (int m = 0; m < 4; m++) {
        const int row0 = brow + wr * 64 + m * 16 + fq * 4;
        #pragma unroll
        for (int n = 0; n < 4; n++) {
            const int col = bcol + wc * 64 + n * 16 + fr;
            const float bv = bias[col];
            #pragma unroll
            for (int r = 0; r < 4; r++) {
                const int row = row0 + r;
                float v = acc[m][n][r] + bv;
                if (MODE == 1) {
                    if (col < D1_DIM) v += Ux[(size_t)row * D1_DIM + col];
                    ((unsigned short*)Out)[(size_t)row * N_DIM + col] = f2bf(rho_f(v));
                } else {
                    ((float*)Out)[(size_t)row * N_DIM + col] = v;
                }
            }
        }
    }
}

extern "C" void kernel_launch(void* const* d_in, const int* in_sizes, int n_in,
                              void* d_out, int out_size, void* d_ws, size_t ws_size,
                              hipStream_t stream) {
    const float* Ux     = (const float*)d_in[0];  // [4096][2048]
    const float* s      = (const float*)d_in[1];  // [4096][4096]
    const float* W      = (const float*)d_in[2];  // [4096][4096]
    const float* b_even = (const float*)d_in[3];  // [4096]
    const float* b_odd  = (const float*)d_in[4];  // [4096]
    const float* Wm     = (const float*)d_in[5];  // [4096][4096]

    char* ws = (char*)d_ws;
    const size_t SZ = (size_t)N_DIM * N_DIM * 2;  // 32 MB per bf16 matrix
    unsigned short* Rs  = (unsigned short*)(ws);
    unsigned short* R2  = (unsigned short*)(ws + SZ);
    unsigned short* Wb  = (unsigned short*)(ws + 2 * SZ);
    unsigned short* WTb = (unsigned short*)(ws + 3 * SZ);

    prep_rs_kernel<<<2048, 256, 0, stream>>>(s, Rs, (N_DIM * N_DIM) / 8);
    prep_w_kernel<<<dim3(128, 128), dim3(32, 8), 0, stream>>>(W, Wm, Wb, WTb);
    // GEMM1: s_odd = Rs @ W  (+b_odd, +Ux, rho) -> R2 bf16
    gemm_kernel<1><<<dim3(32, 32), 256, 0, stream>>>(Rs, WTb, (void*)R2, Ux, b_odd);
    // GEMM2: out = R2 @ W^T (+b_even) -> d_out f32
    gemm_kernel<2><<<dim3(32, 32), 256, 0, stream>>>(R2, Wb, d_out, Ux, b_even);
}

// Round 2
// 480.433 us; speedup vs baseline: 1.0152x; 1.0152x over previous
//
#include <hip/hip_runtime.h>
#include <hip/hip_bf16.h>

// EvenOddFunctionHAM: out = rho(rho(s)@W + b_odd + [Ux|0]) @ W^T + b_even
// W is block-staircase: blocks (0,0),(0,1),(1,1) of 2048^2 nonzero.
// R1 -> R2: + diagonal block swizzle (balances sparse-K blocks across CUs),
//           + double-buffered LDS with next-tile prefetch (T3 2-phase).

#define N_DIM 4096
#define D1_DIM 2048

typedef short short8 __attribute__((ext_vector_type(8)));
typedef float f32x4 __attribute__((ext_vector_type(4)));

__device__ __forceinline__ float rho_f(float x) {
    return 1.0f / (1.0f + __expf(2.0f - 4.0f * x));  // sigmoid(4x-2)
}

__device__ __forceinline__ unsigned short f2bf(float x) {
    unsigned int u = __builtin_bit_cast(unsigned int, x);
    u += 0x7fffu + ((u >> 16) & 1u);
    return (unsigned short)(u >> 16);
}

__device__ __forceinline__ void gl_lds16(const unsigned short* g, unsigned short* l) {
    __builtin_amdgcn_global_load_lds(
        (const __attribute__((address_space(1))) void*)g,
        (__attribute__((address_space(3))) void*)l, 16, 0, 0);
}

// ---------------- prep: Rs = bf16(rho(s)) ----------------
__global__ void prep_rs_kernel(const float* __restrict__ s,
                               unsigned short* __restrict__ Rs, int n8) {
    int t = blockIdx.x * blockDim.x + threadIdx.x;
    int stride = gridDim.x * blockDim.x;
    for (int i = t; i < n8; i += stride) {
        float4 a = ((const float4*)s)[2 * i];
        float4 b = ((const float4*)s)[2 * i + 1];
        unsigned int r0 = f2bf(rho_f(a.x)) | ((unsigned int)f2bf(rho_f(a.y)) << 16);
        unsigned int r1 = f2bf(rho_f(a.z)) | ((unsigned int)f2bf(rho_f(a.w)) << 16);
        unsigned int r2 = f2bf(rho_f(b.x)) | ((unsigned int)f2bf(rho_f(b.y)) << 16);
        unsigned int r3 = f2bf(rho_f(b.z)) | ((unsigned int)f2bf(rho_f(b.w)) << 16);
        uint4 o; o.x = r0; o.y = r1; o.z = r2; o.w = r3;
        ((uint4*)Rs)[i] = o;
    }
}

// ---------------- prep: Wb = bf16(W*mask); WTb = transpose ----------------
__global__ void prep_w_kernel(const float* __restrict__ W,
                              const float* __restrict__ Wm,
                              unsigned short* __restrict__ Wb,
                              unsigned short* __restrict__ WTb) {
    __shared__ unsigned short t[32][33];
    int x = blockIdx.x * 32 + threadIdx.x;
    #pragma unroll
    for (int r = 0; r < 4; r++) {
        int y = blockIdx.y * 32 + threadIdx.y + r * 8;
        size_t idx = (size_t)y * N_DIM + x;
        unsigned short b = f2bf(W[idx] * Wm[idx]);
        Wb[idx] = b;
        t[threadIdx.y + r * 8][threadIdx.x] = b;
    }
    __syncthreads();
    #pragma unroll
    for (int r = 0; r < 4; r++) {
        int yy = threadIdx.y + r * 8;
        int orow = blockIdx.x * 32 + yy;
        int ocol = blockIdx.y * 32 + threadIdx.x;
        WTb[(size_t)orow * N_DIM + ocol] = t[threadIdx.x][yy];
    }
}

// ---------------- GEMM: C = A @ Bt^T  (A[M][K], Bt[N][K], bf16, fp32 acc) --
// 128x128 tile, BK=32, 4 waves (2x2), 4x4 16x16x32 fragments per wave.
// Double-buffered LDS, next-tile prefetch, 1 barrier per K-step.
// MODE 1: out = bf16(rho(acc + b_odd[col] + (col<D1 ? Ux : 0)))   (R2, bf16)
// MODE 2: out = acc + b_even[col]                                  (d_out, f32)
template<int MODE>
__global__ __launch_bounds__(256) void gemm_kernel(
    const unsigned short* __restrict__ A,
    const unsigned short* __restrict__ Bt,
    void* __restrict__ Out,
    const float* __restrict__ Ux,
    const float* __restrict__ bias) {
    __shared__ unsigned short As[2 * 128 * 32];
    __shared__ unsigned short Bs[2 * 128 * 32];

    // diagonal block swizzle: per-CU id set {i, i+256, i+512, i+768} gets
    // bx offsets {0,8,16,24} -> 2 light + 2 heavy sparse-K blocks per CU
    const int id = blockIdx.x;
    const int nby = id >> 5;
    const int nbx = (id + nby) & 31;
    const int brow = nby * 128;
    const int bcol = nbx * 128;

    const int tid = threadIdx.x;
    const int wid = tid >> 6;
    const int lane = tid & 63;
    const int wr = wid >> 1, wc = wid & 1;

    // block-sparse K range (skipped region of Bt is all-zero anyway)
    int kbeg, kend;
    if (MODE == 1) { kbeg = 0; kend = (bcol < D1_DIM) ? D1_DIM : N_DIM; }
    else           { kbeg = (bcol < D1_DIM) ? 0 : D1_DIM; kend = N_DIM; }

    // staging: each wave stages 2 chunks (1KB each) of A and of B
    const int c0 = wid * 2;
    const int srow = c0 * 16 + (lane >> 2);
    const int scol = (lane & 3) << 3;
    const unsigned short* gA0 = A  + (size_t)(brow + srow) * N_DIM + scol + kbeg;
    const unsigned short* gA1 = gA0 + 16 * N_DIM;
    const unsigned short* gB0 = Bt + (size_t)(bcol + srow) * N_DIM + scol + kbeg;
    const unsigned short* gB1 = gB0 + 16 * N_DIM;

    f32x4 acc[4][4];
    #pragma unroll
    for (int m = 0; m < 4; m++)
        #pragma unroll
        for (int n = 0; n < 4; n++)
            acc[m][n] = (f32x4){0.f, 0.f, 0.f, 0.f};

    const int fr = lane & 15;
    const int fq = lane >> 4;
    const int raoff = (wr * 64 + fr) * 32 + fq * 8;
    const int rboff = (wc * 64 + fr) * 32 + fq * 8;

#define STAGE(buf, ko) do {                                   \
        unsigned short* la = &As[(buf) * 4096 + c0 * 512];    \
        unsigned short* lb = &Bs[(buf) * 4096 + c0 * 512];    \
        gl_lds16(gA0 + (ko), la);                             \
        gl_lds16(gA1 + (ko), la + 512);                       \
        gl_lds16(gB0 + (ko), lb);                             \
        gl_lds16(gB1 + (ko), lb + 512);                       \
    } while (0)

    auto compute = [&](int buf) {
        const unsigned short* rA = &As[buf * 4096 + raoff];
        const unsigned short* rB = &Bs[buf * 4096 + rboff];
        short8 af[4], bq[4];
        #pragma unroll
        for (int m = 0; m < 4; m++)
            af[m] = *(const short8*)(rA + m * 16 * 32);
        #pragma unroll
        for (int n = 0; n < 4; n++)
            bq[n] = *(const short8*)(rB + n * 16 * 32);
        #pragma unroll
        for (int m = 0; m < 4; m++)
            #pragma unroll
            for (int n = 0; n < 4; n++)
                acc[m][n] = __builtin_amdgcn_mfma_f32_16x16x32_bf16(
                    af[m], bq[n], acc[m][n], 0, 0, 0);
    };

    const int nk = (kend - kbeg) >> 5;
    STAGE(0, 0);
    __syncthreads();   // drains vmcnt(0): buf0 ready
    int cur = 0;
    for (int t = 0; t < nk - 1; t++) {
        STAGE(cur ^ 1, (t + 1) << 5);   // prefetch next tile (overlaps MFMA)
        compute(cur);
        __syncthreads();                // drains vmcnt(0)+lgkmcnt(0)
        cur ^= 1;
    }
    compute(cur);
#undef STAGE

    // epilogue: C/D layout col = lane&15, row = (lane>>4)*4 + reg
    #pragma unroll
    for (int m = 0; m < 4; m++) {
        const int row0 = brow + wr * 64 + m * 16 + fq * 4;
        #pragma unroll
        for (int n = 0; n < 4; n++) {
            const int col = bcol + wc * 64 + n * 16 + fr;
            const float bv = bias[col];
            #pragma unroll
            for (int r = 0; r < 4; r++) {
                const int row = row0 + r;
                float v = acc[m][n][r] + bv;
                if (MODE == 1) {
                    if (col < D1_DIM) v += Ux[(size_t)row * D1_DIM + col];
                    ((unsigned short*)Out)[(size_t)row * N_DIM + col] = f2bf(rho_f(v));
                } else {
                    ((float*)Out)[(size_t)row * N_DIM + col] = v;
                }
            }
        }
    }
}

extern "C" void kernel_launch(void* const* d_in, const int* in_sizes, int n_in,
                              void* d_out, int out_size, void* d_ws, size_t ws_size,
                              hipStream_t stream) {
    const float* Ux     = (const float*)d_in[0];  // [4096][2048]
    const float* s      = (const float*)d_in[1];  // [4096][4096]
    const float* W      = (const float*)d_in[2];  // [4096][4096]
    const float* b_even = (const float*)d_in[3];  // [4096]
    const float* b_odd  = (const float*)d_in[4];  // [4096]
    const float* Wm     = (const float*)d_in[5];  // [4096][4096]

    char* ws = (char*)d_ws;
    const size_t SZ = (size_t)N_DIM * N_DIM * 2;  // 32 MB per bf16 matrix
    unsigned short* Rs  = (unsigned short*)(ws);
    unsigned short* R2  = (unsigned short*)(ws + SZ);
    unsigned short* Wb  = (unsigned short*)(ws + 2 * SZ);
    unsigned short* WTb = (unsigned short*)(ws + 3 * SZ);

    prep_rs_kernel<<<2048, 256, 0, stream>>>(s, Rs, (N_DIM * N_DIM) / 8);
    prep_w_kernel<<<dim3(128, 128), dim3(32, 8), 0, stream>>>(W, Wm, Wb, WTb);
    // GEMM1: s_odd = Rs @ W  (+b_odd, +Ux, rho) -> R2 bf16
    gemm_kernel<1><<<1024, 256, 0, stream>>>(Rs, WTb, (void*)R2, Ux, b_odd);
    // GEMM2: out = R2 @ W^T (+b_even) -> d_out f32
    gemm_kernel<2><<<1024, 256, 0, stream>>>(R2, Wb, d_out, Ux, b_even);
}

// Round 3
// 287.464 us; speedup vs baseline: 1.6968x; 1.6713x over previous
//
#include <hip/hip_runtime.h>
#include <hip/hip_bf16.h>

// EvenOddFunctionHAM: out = rho(rho(s)@W + b_odd + [Ux|0]) @ W^T + b_even
// R2 -> R3: 256x256 8-phase template (m201): BK=64, 8 waves, T2 chunk-XOR
// LDS swizzle (source-side + read-side), counted vmcnt(4) (never 0),
// setprio around MFMA clusters, bijective XCD block remap.

#define N_DIM 4096
#define D1_DIM 2048

typedef short short8 __attribute__((ext_vector_type(8)));
typedef float f32x4 __attribute__((ext_vector_type(4)));

__device__ __forceinline__ float rho_f(float x) {
    return 1.0f / (1.0f + __expf(2.0f - 4.0f * x));  // sigmoid(4x-2)
}

__device__ __forceinline__ unsigned short f2bf(float x) {
    unsigned int u = __builtin_bit_cast(unsigned int, x);
    u += 0x7fffu + ((u >> 16) & 1u);
    return (unsigned short)(u >> 16);
}

__device__ __forceinline__ void gl_lds16(const unsigned short* g, void* l) {
    __builtin_amdgcn_global_load_lds(
        (const __attribute__((address_space(1))) void*)g,
        (__attribute__((address_space(3))) void*)l, 16, 0, 0);
}

// ---------------- prep: Rs = bf16(rho(s)) ----------------
__global__ void prep_rs_kernel(const float* __restrict__ s,
                               unsigned short* __restrict__ Rs, int n8) {
    int t = blockIdx.x * blockDim.x + threadIdx.x;
    int stride = gridDim.x * blockDim.x;
    for (int i = t; i < n8; i += stride) {
        float4 a = ((const float4*)s)[2 * i];
        float4 b = ((const float4*)s)[2 * i + 1];
        unsigned int r0 = f2bf(rho_f(a.x)) | ((unsigned int)f2bf(rho_f(a.y)) << 16);
        unsigned int r1 = f2bf(rho_f(a.z)) | ((unsigned int)f2bf(rho_f(a.w)) << 16);
        unsigned int r2 = f2bf(rho_f(b.x)) | ((unsigned int)f2bf(rho_f(b.y)) << 16);
        unsigned int r3 = f2bf(rho_f(b.z)) | ((unsigned int)f2bf(rho_f(b.w)) << 16);
        uint4 o; o.x = r0; o.y = r1; o.z = r2; o.w = r3;
        ((uint4*)Rs)[i] = o;
    }
}

// ---------------- prep: Wb = bf16(W*mask); WTb = transpose ----------------
__global__ void prep_w_kernel(const float* __restrict__ W,
                              const float* __restrict__ Wm,
                              unsigned short* __restrict__ Wb,
                              unsigned short* __restrict__ WTb) {
    __shared__ unsigned short t[32][33];
    int x = blockIdx.x * 32 + threadIdx.x;
    #pragma unroll
    for (int r = 0; r < 4; r++) {
        int y = blockIdx.y * 32 + threadIdx.y + r * 8;
        size_t idx = (size_t)y * N_DIM + x;
        unsigned short b = f2bf(W[idx] * Wm[idx]);
        Wb[idx] = b;
        t[threadIdx.y + r * 8][threadIdx.x] = b;
    }
    __syncthreads();
    #pragma unroll
    for (int r = 0; r < 4; r++) {
        int yy = threadIdx.y + r * 8;
        int orow = blockIdx.x * 32 + yy;
        int ocol = blockIdx.y * 32 + threadIdx.x;
        WTb[(size_t)orow * N_DIM + ocol] = t[threadIdx.x][yy];
    }
}

// ---------------- GEMM 256x256, BK=64, 8 waves, 8-phase ----------------
// C = A @ Bt^T. A[M][K], Bt[N][K] bf16 row-major (ld=4096), fp32 acc.
// LDS per buf: A[256][64] (2 halves of 128 rows) + B[256][64]. 2 bufs = 128KB.
// Swizzle: LDS[r][chunk c] holds G[r][c ^ (r&7)] (chunk = 16B); applied on
// the global SOURCE during global_load_lds (linear dest) and on ds_read.
template<int MODE>
__global__ __launch_bounds__(512, 2) void gemm_kernel(
    const unsigned short* __restrict__ A,
    const unsigned short* __restrict__ Bt,
    void* __restrict__ Out,
    const float* __restrict__ Ux,
    const float* __restrict__ bias) {
    __shared__ char lds[131072];

    // bijective XCD chunk remap (256 blocks, 8 XCDs): XCD x -> tile-rows {2x,2x+1}
    const int id = blockIdx.x;
    const int wg = ((id & 7) << 5) | (id >> 3);
    const int by = wg >> 4, bx = wg & 15;
    const int brow = by << 8, bcol = bx << 8;

    const int tid = threadIdx.x;
    const int w = tid >> 6;        // wave 0..7
    const int L = tid & 63;
    const int wr = w >> 2;         // 0..1 : rows wr*128..+127
    const int wc = w & 3;          // 0..3 : cols wc*64..+63
    const int fr = L & 15;
    const int fq = L >> 4;
    const int swz = fr & 7;

    // block-sparse K range (exact: skipped W blocks are all-zero)
    int kbeg, kend;
    if (MODE == 1) { kbeg = 0; kend = (bcol < D1_DIM) ? D1_DIM : N_DIM; }
    else           { kbeg = (bcol < D1_DIM) ? 0 : D1_DIM; kend = N_DIM; }

    // ---- staging geometry: half-tile = 128 rows x 64 cols = 16KB ----
    // per thread: 2 x gl_lds16; wave w covers rows w*16 + i*8 + (L>>3)
    const int srow8 = w * 16 + (L >> 3);               // + i*8 + h*128
    const int scol = ((L & 7) ^ (L >> 3)) << 3;        // swizzled source chunk
    // LDS wave-uniform dest base (lane*16 added by HW): w*2048 + i*1024
#define STAGE_HALF(mat, gbase, h, kt, bb, isB) do {                            \
        const unsigned short* gs_ = (mat) +                                    \
            (size_t)((gbase) + (h) * 128 + srow8) * N_DIM +                    \
            (kbeg + ((kt) << 6) + scol);                                       \
        char* ld_ = lds + (bb) * 65536 + (isB) * 32768 + (h) * 16384 + w * 2048;\
        gl_lds16(gs_, ld_);                                                    \
        gl_lds16(gs_ + 8 * N_DIM, ld_ + 1024);                                 \
    } while (0)

    // ---- fragment read bases (byte offsets within a buffer) ----
    const int abase = wr * 16384 + fr * 128;
    const int bbase = 32768 + (wc >> 1) * 16384 + (((wc & 1) * 64 + fr) * 128);

    short8 af[2][4], bf0[2][2], bf1[2][2];
#define LDA(bb, qm) do {                                                       \
        _Pragma("unroll") for (int s_ = 0; s_ < 2; ++s_)                       \
        _Pragma("unroll") for (int m_ = 0; m_ < 4; ++m_)                       \
            af[s_][m_] = *(const short8*)(lds + (bb) * 65536 + abase +         \
                ((qm) * 64 + m_ * 16) * 128 + (((4 * s_ + fq) ^ swz) << 4));   \
    } while (0)
#define LDB(bb, qn, dst) do {                                                  \
        _Pragma("unroll") for (int s_ = 0; s_ < 2; ++s_)                       \
        _Pragma("unroll") for (int n_ = 0; n_ < 2; ++n_)                       \
            dst[s_][n_] = *(const short8*)(lds + (bb) * 65536 + bbase +        \
                ((qn) * 32 + n_ * 16) * 128 + (((4 * s_ + fq) ^ swz) << 4));   \
    } while (0)

    f32x4 acc[8][4];
    #pragma unroll
    for (int i = 0; i < 8; i++)
        #pragma unroll
        for (int j = 0; j < 4; j++)
            acc[i][j] = (f32x4){0.f, 0.f, 0.f, 0.f};

#define MFMA_Q(qm, qn, bfr) do {                                               \
        __builtin_amdgcn_s_setprio(1);                                         \
        _Pragma("unroll") for (int s_ = 0; s_ < 2; ++s_)                       \
        _Pragma("unroll") for (int m_ = 0; m_ < 4; ++m_)                       \
        _Pragma("unroll") for (int n_ = 0; n_ < 2; ++n_)                       \
            acc[(qm) * 4 + m_][(qn) * 2 + n_] =                                \
                __builtin_amdgcn_mfma_f32_16x16x32_bf16(                       \
                    af[s_][m_], bfr[s_][n_], acc[(qm) * 4 + m_][(qn) * 2 + n_],\
                    0, 0, 0);                                                  \
        __builtin_amdgcn_s_setprio(0);                                         \
    } while (0)

#define LGKM0() do { asm volatile("s_waitcnt lgkmcnt(0)" ::: "memory");        \
                     __builtin_amdgcn_sched_barrier(0); } while (0)

    const int nk = (kend - kbeg) >> 6;   // 32 or 64 (power of 2)
    const int km = nk - 1;               // wrap mask for tail stages

    // ---- prologue: t0 fully + t1.B halves; leaves exactly 4 loads in flight
    STAGE_HALF(A, brow, 0, 0, 0, 0);
    STAGE_HALF(A, brow, 1, 0, 0, 0);
    STAGE_HALF(Bt, bcol, 0, 0, 0, 1);
    STAGE_HALF(Bt, bcol, 1, 0, 0, 1);
    STAGE_HALF(Bt, bcol, 0, 1 & km, 1, 1);
    STAGE_HALF(Bt, bcol, 1, 1 & km, 1, 1);
    asm volatile("s_waitcnt vmcnt(4)" ::: "memory");
    __builtin_amdgcn_s_barrier();

    for (int t = 0; t < nk; ++t) {
        const int c = t & 1;
        const int t1 = (t + 1) & km;     // wrapped: tail stages hit valid
        const int t2 = (t + 2) & km;     // addresses, land in dead buffers

        // phase 1: quad (0,0); stage next-tile A half0 -> buf c^1
        LDA(c, 0); LDB(c, 0, bf0);
        STAGE_HALF(A, brow, 0, t1, c ^ 1, 0);
        __builtin_amdgcn_s_barrier();
        LGKM0();
        MFMA_Q(0, 0, bf0);
        __builtin_amdgcn_s_barrier();

        // phase 2: quad (0,1); stage next-tile A half1
        LDB(c, 1, bf1);
        STAGE_HALF(A, brow, 1, t1, c ^ 1, 0);
        __builtin_amdgcn_s_barrier();
        LGKM0();
        MFMA_Q(0, 1, bf1);
        __builtin_amdgcn_s_barrier();

        // phase 3: quad (1,0); stage tile t+2's B half0 -> buf c
        // (buf c's B slots were last read in phases 1-2, drained + barriered)
        LDA(c, 1);
        STAGE_HALF(Bt, bcol, 0, t2, c, 1);
        __builtin_amdgcn_s_barrier();
        LGKM0();
        MFMA_Q(1, 0, bf0);
        __builtin_amdgcn_s_barrier();

        // phase 4: quad (1,1); stage tile t+2's B half1; counted vmcnt:
        // completes tile t+1 entirely, leaves t+2's 2 B-halves in flight
        STAGE_HALF(Bt, bcol, 1, t2, c, 1);
        asm volatile("s_waitcnt vmcnt(4)" ::: "memory");
        __builtin_amdgcn_s_barrier();
        LGKM0();
        MFMA_Q(1, 1, bf1);
        __builtin_amdgcn_s_barrier();
    }

    // ---- epilogue: C/D layout col = fr (N), row = fq*4 + reg (M) ----
    const bool hasUx = (MODE == 1) && (bcol < D1_DIM);
    #pragma unroll
    for (int qm = 0; qm < 2; qm++)
        #pragma unroll
        for (int m = 0; m < 4; m++) {
            const int row0 = brow + wr * 128 + qm * 64 + m * 16 + fq * 4;
            #pragma unroll
            for (int qn = 0; qn < 2; qn++)
                #pragma unroll
                for (int n = 0; n < 2; n++) {
                    const int col = bcol + wc * 64 + qn * 32 + n * 16 + fr;
                    const float bv = bias[col];
                    #pragma unroll
                    for (int r = 0; r < 4; r++) {
                        const int row = row0 + r;
                        float v = acc[qm * 4 + m][qn * 2 + n][r] + bv;
                        if (MODE == 1) {
                            if (hasUx) v += Ux[(size_t)row * D1_DIM + col];
                            ((unsigned short*)Out)[(size_t)row * N_DIM + col] =
                                f2bf(rho_f(v));
                        } else {
                            ((float*)Out)[(size_t)row * N_DIM + col] = v;
                        }
                    }
                }
        }
#undef STAGE_HALF
#undef LDA
#undef LDB
#undef MFMA_Q
#undef LGKM0
}

extern "C" void kernel_launch(void* const* d_in, const int* in_sizes, int n_in,
                              void* d_out, int out_size, void* d_ws, size_t ws_size,
                              hipStream_t stream) {
    const float* Ux     = (const float*)d_in[0];  // [4096][2048]
    const float* s      = (const float*)d_in[1];  // [4096][4096]
    const float* W      = (const float*)d_in[2];  // [4096][4096]
    const float* b_even = (const float*)d_in[3];  // [4096]
    const float* b_odd  = (const float*)d_in[4];  // [4096]
    const float* Wm     = (const float*)d_in[5];  // [4096][4096]

    char* ws = (char*)d_ws;
    const size_t SZ = (size_t)N_DIM * N_DIM * 2;  // 32 MB per bf16 matrix
    unsigned short* Rs  = (unsigned short*)(ws);
    unsigned short* R2  = (unsigned short*)(ws + SZ);
    unsigned short* Wb  = (unsigned short*)(ws + 2 * SZ);
    unsigned short* WTb = (unsigned short*)(ws + 3 * SZ);

    prep_rs_kernel<<<2048, 256, 0, stream>>>(s, Rs, (N_DIM * N_DIM) / 8);
    prep_w_kernel<<<dim3(128, 128), dim3(32, 8), 0, stream>>>(W, Wm, Wb, WTb);
    // GEMM1: s_odd = Rs @ W  (+b_odd, +Ux, rho) -> R2 bf16
    gemm_kernel<1><<<256, 512, 0, stream>>>(Rs, WTb, (void*)R2, Ux, b_odd);
    // GEMM2: out = R2 @ W^T (+b_even) -> d_out f32
    gemm_kernel<2><<<256, 512, 0, stream>>>(R2, Wb, d_out, Ux, b_even);
}

// Round 4
// 283.468 us; speedup vs baseline: 1.7207x; 1.0141x over previous
//
#include <hip/hip_runtime.h>
#include <hip/hip_bf16.h>

// EvenOddFunctionHAM: out = rho(rho(s)@W + b_odd + [Ux|0]) @ W^T + b_even
// R3 -> R4: BN 256->128 (512 blocks, heavy-first order => each CU runs
// exactly 1 heavy + 1 light block: balanced 0.75x critical path);
// triple-buffered LDS (3 x 48KB), stage tile t+2 during t, vmcnt(6);
// drop W_mask read (zero block never read); post-loop vmcnt(0) drain.

#define N_DIM 4096
#define D1_DIM 2048
#define BUFSZ 49152          // 48KB: A[256][64] (32KB) + B[128][64] (16KB)
#define LDSSZ 147456         // 3 buffers

typedef short short8 __attribute__((ext_vector_type(8)));
typedef float f32x4 __attribute__((ext_vector_type(4)));

__device__ __forceinline__ float rho_f(float x) {
    return 1.0f / (1.0f + __expf(2.0f - 4.0f * x));  // sigmoid(4x-2)
}

__device__ __forceinline__ unsigned short f2bf(float x) {
    unsigned int u = __builtin_bit_cast(unsigned int, x);
    u += 0x7fffu + ((u >> 16) & 1u);
    return (unsigned short)(u >> 16);
}

__device__ __forceinline__ void gl_lds16(const unsigned short* g, void* l) {
    __builtin_amdgcn_global_load_lds(
        (const __attribute__((address_space(1))) void*)g,
        (__attribute__((address_space(3))) void*)l, 16, 0, 0);
}

// ---------------- prep: Rs = bf16(rho(s)) ----------------
__global__ void prep_rs_kernel(const float* __restrict__ s,
                               unsigned short* __restrict__ Rs, int n8) {
    int t = blockIdx.x * blockDim.x + threadIdx.x;
    int stride = gridDim.x * blockDim.x;
    for (int i = t; i < n8; i += stride) {
        float4 a = ((const float4*)s)[2 * i];
        float4 b = ((const float4*)s)[2 * i + 1];
        unsigned int r0 = f2bf(rho_f(a.x)) | ((unsigned int)f2bf(rho_f(a.y)) << 16);
        unsigned int r1 = f2bf(rho_f(a.z)) | ((unsigned int)f2bf(rho_f(a.w)) << 16);
        unsigned int r2 = f2bf(rho_f(b.x)) | ((unsigned int)f2bf(rho_f(b.y)) << 16);
        unsigned int r3 = f2bf(rho_f(b.z)) | ((unsigned int)f2bf(rho_f(b.w)) << 16);
        uint4 o; o.x = r0; o.y = r1; o.z = r2; o.w = r3;
        ((uint4*)Rs)[i] = o;
    }
}

// ------- prep: Wb = bf16(W); WTb = transpose. Block (1,0) of W is never
// read by either GEMM's K-ranges -> skip it entirely (no mask input). -------
__global__ void prep_w_kernel(const float* __restrict__ W,
                              unsigned short* __restrict__ Wb,
                              unsigned short* __restrict__ WTb) {
    if (blockIdx.y * 32 >= D1_DIM && blockIdx.x * 32 < D1_DIM) return;  // dead
    __shared__ unsigned short t[32][33];
    int x = blockIdx.x * 32 + threadIdx.x;
    #pragma unroll
    for (int r = 0; r < 4; r++) {
        int y = blockIdx.y * 32 + threadIdx.y + r * 8;
        size_t idx = (size_t)y * N_DIM + x;
        unsigned short b = f2bf(W[idx]);
        Wb[idx] = b;
        t[threadIdx.y + r * 8][threadIdx.x] = b;
    }
    __syncthreads();
    #pragma unroll
    for (int r = 0; r < 4; r++) {
        int yy = threadIdx.y + r * 8;
        int orow = blockIdx.x * 32 + yy;
        int ocol = blockIdx.y * 32 + threadIdx.x;
        WTb[(size_t)orow * N_DIM + ocol] = t[threadIdx.x][yy];
    }
}

// ---------------- GEMM 256x128, BK=64, 8 waves, 2 phases/K-tile ----------
// C = A @ Bt^T. A[M][K], Bt[N][K] bf16 row-major (ld=4096), fp32 acc.
// Buf (48KB): A[256][64] at 0, B[128][64] at 32768. 3 bufs, t+2 prefetch.
// Swizzle: chunk c of row r holds global chunk c^(r&7); source-side on
// global_load_lds (linear LDS dest), read-side on ds_read.
template<int MODE>
__global__ __launch_bounds__(512, 2) void gemm_kernel(
    const unsigned short* __restrict__ A,
    const unsigned short* __restrict__ Bt,
    void* __restrict__ Out,
    const float* __restrict__ Ux,
    const float* __restrict__ bias) {
    __shared__ __align__(16) char lds[LDSSZ];

    // heavy-first ordering + per-group XCD remap.
    // group 0 (ids 0..255) = heavy K tiles, group 1 = light.
    const int id = blockIdx.x;
    const int grp = id >> 8;
    const int i = id & 255;
    const int tile = ((i & 7) << 5) | (i >> 3);   // XCD x -> tile rows {2x,2x+1}
    const int by = tile >> 4;
    const int bxh = tile & 15;
    int bx;
    if (MODE == 1) bx = grp ? bxh : 16 + bxh;     // heavy: bcol >= 2048
    else           bx = grp ? 16 + bxh : bxh;     // heavy: bcol < 2048
    const int brow = by << 8;
    const int bcol = bx << 7;

    const int tid = threadIdx.x;
    const int w = tid >> 6;
    const int L = tid & 63;
    const int wr = w >> 2;        // 0..1 : rows wr*128..+127
    const int wc = w & 3;         // 0..3 : cols wc*32..+31
    const int fr = L & 15;
    const int fq = L >> 4;
    const int swz = fr & 7;

    // block-sparse K range (exact: skipped W blocks are all-zero)
    int kbeg, kend;
    if (MODE == 1) { kbeg = 0; kend = (bcol < D1_DIM) ? D1_DIM : N_DIM; }
    else           { kbeg = (bcol < D1_DIM) ? 0 : D1_DIM; kend = N_DIM; }

    // ---- one staging round = 1 gl_lds16/thread covering 64 rows x 64 cols
    // lane row = rbase + w*8 + (L>>3); chunk = (L&7)^(row&7) (row&7 == L>>3)
    const int srl = w * 8 + (L >> 3);
    const int schunk8 = (((L & 7) ^ (L >> 3)) << 3);
    const int wbase = w * 1024;
#define STAGE1(mat, grow0, rbase, regbyte, kcol, bufoff) do {                  \
        const unsigned short* gs_ = (mat) +                                    \
            (size_t)((grow0) + (rbase) + srl) * N_DIM + (kcol) + schunk8;      \
        gl_lds16(gs_, lds + (bufoff) + (regbyte) + (rbase) * 128 + wbase);     \
    } while (0)
#define STAGE_A3(kcol, bufoff) do {                                           \
        STAGE1(A, brow, 0, 0, kcol, bufoff);                                  \
        STAGE1(A, brow, 64, 0, kcol, bufoff);                                 \
        STAGE1(A, brow, 128, 0, kcol, bufoff); } while (0)
#define STAGE_AB3(kcol, bufoff) do {                                          \
        STAGE1(A, brow, 192, 0, kcol, bufoff);                                \
        STAGE1(Bt, bcol, 0, 32768, kcol, bufoff);                             \
        STAGE1(Bt, bcol, 64, 32768, kcol, bufoff); } while (0)

    short8 af[2][4], bf[2][2];
#define LDA(bufoff, qm) do {                                                  \
        _Pragma("unroll") for (int s_ = 0; s_ < 2; ++s_)                      \
        _Pragma("unroll") for (int m_ = 0; m_ < 4; ++m_) {                    \
            const int R_ = wr * 128 + (qm) * 64 + m_ * 16 + fr;               \
            af[s_][m_] = *(const short8*)(lds + (bufoff) + R_ * 128 +         \
                (((4 * s_ + fq) ^ swz) << 4)); }                              \
    } while (0)
#define LDB(bufoff) do {                                                      \
        _Pragma("unroll") for (int s_ = 0; s_ < 2; ++s_)                      \
        _Pragma("unroll") for (int n_ = 0; n_ < 2; ++n_) {                    \
            const int R_ = wc * 32 + n_ * 16 + fr;                            \
            bf[s_][n_] = *(const short8*)(lds + (bufoff) + 32768 + R_ * 128 + \
                (((4 * s_ + fq) ^ swz) << 4)); }                              \
    } while (0)

    f32x4 acc[8][2];
    #pragma unroll
    for (int m = 0; m < 8; m++) {
        acc[m][0] = (f32x4){0.f, 0.f, 0.f, 0.f};
        acc[m][1] = (f32x4){0.f, 0.f, 0.f, 0.f};
    }

#define MFMA_Q(qm) do {                                                       \
        __builtin_amdgcn_s_setprio(1);                                        \
        _Pragma("unroll") for (int s_ = 0; s_ < 2; ++s_)                      \
        _Pragma("unroll") for (int m_ = 0; m_ < 4; ++m_)                      \
        _Pragma("unroll") for (int n_ = 0; n_ < 2; ++n_)                      \
            acc[(qm) * 4 + m_][n_] = __builtin_amdgcn_mfma_f32_16x16x32_bf16( \
                af[s_][m_], bf[s_][n_], acc[(qm) * 4 + m_][n_], 0, 0, 0);     \
        __builtin_amdgcn_s_setprio(0);                                        \
    } while (0)

#define LGKM0() do { asm volatile("s_waitcnt lgkmcnt(0)" ::: "memory");       \
                     __builtin_amdgcn_sched_barrier(0); } while (0)

    const int nk = (kend - kbeg) >> 6;   // 32 or 64
    const int km = nk - 1;

    // ---- prologue: tile0 -> buf0, tile1 -> buf1 (12 loads); t0 ready
    {
        const int kc0 = kbeg;
        const int kc1 = kbeg + ((1 & km) << 6);
        STAGE_A3(kc0, 0); STAGE_AB3(kc0, 0);
        STAGE_A3(kc1, BUFSZ); STAGE_AB3(kc1, BUFSZ);
        asm volatile("s_waitcnt vmcnt(6)" ::: "memory");
        __builtin_amdgcn_s_barrier();
    }

    int cb = 0;           // buf byte-offset of tile t
    int sb = 2 * BUFSZ;   // buf byte-offset of tile t+2 (stage target)
    for (int t = 0; t < nk; ++t) {
        const int kc2 = kbeg + (((t + 2) & km) << 6);
        // phase 0: frags for qm=0 + full B; stage 3 rounds of tile t+2
        LDB(cb);
        LDA(cb, 0);
        STAGE_A3(kc2, sb);
        __builtin_amdgcn_s_barrier();
        LGKM0();
        MFMA_Q(0);
        __builtin_amdgcn_s_barrier();
        // phase 1: frags for qm=1; stage remaining 3 rounds; counted vmcnt:
        // completes tile t+1 (issued during t-1), leaves t+2's 6 in flight
        LDA(cb, 1);
        STAGE_AB3(kc2, sb);
        asm volatile("s_waitcnt vmcnt(6)" ::: "memory");
        __builtin_amdgcn_s_barrier();
        LGKM0();
        MFMA_Q(1);
        __builtin_amdgcn_s_barrier();
        cb += BUFSZ; if (cb == LDSSZ) cb = 0;
        sb += BUFSZ; if (sb == LDSSZ) sb = 0;
    }
    // drain dead tail stages: must not land in the NEXT block's LDS
    asm volatile("s_waitcnt vmcnt(0)" ::: "memory");

    // ---- epilogue: C/D layout col = fr (N), row = fq*4 + reg (M) ----
    const bool hasUx = (MODE == 1) && (bcol < D1_DIM);
    #pragma unroll
    for (int n = 0; n < 2; ++n) {
        const int col = bcol + wc * 32 + n * 16 + fr;
        const float bv = bias[col];
        #pragma unroll
        for (int q8 = 0; q8 < 8; ++q8) {          // q8 = qm*4+m -> row q8*16
            const int row0 = brow + wr * 128 + q8 * 16 + fq * 4;
            #pragma unroll
            for (int r = 0; r < 4; ++r) {
                const int row = row0 + r;
                float v = acc[q8][n][r] + bv;
                if (MODE == 1) {
                    if (hasUx) v += Ux[(size_t)row * D1_DIM + col];
                    ((unsigned short*)Out)[(size_t)row * N_DIM + col] =
                        f2bf(rho_f(v));
                } else {
                    ((float*)Out)[(size_t)row * N_DIM + col] = v;
                }
            }
        }
    }
#undef STAGE1
#undef STAGE_A3
#undef STAGE_AB3
#undef LDA
#undef LDB
#undef MFMA_Q
#undef LGKM0
}

extern "C" void kernel_launch(void* const* d_in, const int* in_sizes, int n_in,
                              void* d_out, int out_size, void* d_ws, size_t ws_size,
                              hipStream_t stream) {
    const float* Ux     = (const float*)d_in[0];  // [4096][2048]
    const float* s      = (const float*)d_in[1];  // [4096][4096]
    const float* W      = (const float*)d_in[2];  // [4096][4096]
    const float* b_even = (const float*)d_in[3];  // [4096]
    const float* b_odd  = (const float*)d_in[4];  // [4096]
    // d_in[5] = W_mask: unused (masked block is never read)

    char* ws = (char*)d_ws;
    const size_t SZ = (size_t)N_DIM * N_DIM * 2;  // 32 MB per bf16 matrix
    unsigned short* Rs  = (unsigned short*)(ws);
    unsigned short* R2  = (unsigned short*)(ws + SZ);
    unsigned short* Wb  = (unsigned short*)(ws + 2 * SZ);
    unsigned short* WTb = (unsigned short*)(ws + 3 * SZ);

    prep_rs_kernel<<<2048, 256, 0, stream>>>(s, Rs, (N_DIM * N_DIM) / 8);
    prep_w_kernel<<<dim3(128, 128), dim3(32, 8), 0, stream>>>(W, Wb, WTb);
    // GEMM1: s_odd = Rs @ W  (+b_odd, +Ux, rho) -> R2 bf16
    gemm_kernel<1><<<512, 512, 0, stream>>>(Rs, WTb, (void*)R2, Ux, b_odd);
    // GEMM2: out = R2 @ W^T (+b_even) -> d_out f32
    gemm_kernel<2><<<512, 512, 0, stream>>>(R2, Wb, d_out, Ux, b_even);
}

// Round 5
// 273.872 us; speedup vs baseline: 1.7810x; 1.0350x over previous
//
#include <hip/hip_runtime.h>
#include <hip/hip_bf16.h>

// EvenOddFunctionHAM: out = rho(rho(s)@W + b_odd + [Ux|0]) @ W^T + b_even
// R4 -> R5: revert to R3's 256x256/8-wave geometry (BN=128 was LDS-read-
// bound); deepen the pipeline: A triple-buffered (stage A(t+2) at p1-p2,
// 6-7 phases of HBM-latency cover), B double-buffered (same-tile slot
// reuse), vmcnt(8) once per K-tile. LDS = 3*32K + 2*32K = 160KB exactly.

#define N_DIM 4096
#define D1_DIM 2048

typedef short short8 __attribute__((ext_vector_type(8)));
typedef float f32x4 __attribute__((ext_vector_type(4)));

__device__ __forceinline__ float rho_f(float x) {
    return 1.0f / (1.0f + __expf(2.0f - 4.0f * x));  // sigmoid(4x-2)
}

__device__ __forceinline__ unsigned short f2bf(float x) {
    unsigned int u = __builtin_bit_cast(unsigned int, x);
    u += 0x7fffu + ((u >> 16) & 1u);
    return (unsigned short)(u >> 16);
}

__device__ __forceinline__ void gl_lds16(const unsigned short* g, void* l) {
    __builtin_amdgcn_global_load_lds(
        (const __attribute__((address_space(1))) void*)g,
        (__attribute__((address_space(3))) void*)l, 16, 0, 0);
}

// ---------------- prep: Rs = bf16(rho(s)) ----------------
__global__ void prep_rs_kernel(const float* __restrict__ s,
                               unsigned short* __restrict__ Rs, int n8) {
    int t = blockIdx.x * blockDim.x + threadIdx.x;
    int stride = gridDim.x * blockDim.x;
    for (int i = t; i < n8; i += stride) {
        float4 a = ((const float4*)s)[2 * i];
        float4 b = ((const float4*)s)[2 * i + 1];
        unsigned int r0 = f2bf(rho_f(a.x)) | ((unsigned int)f2bf(rho_f(a.y)) << 16);
        unsigned int r1 = f2bf(rho_f(a.z)) | ((unsigned int)f2bf(rho_f(a.w)) << 16);
        unsigned int r2 = f2bf(rho_f(b.x)) | ((unsigned int)f2bf(rho_f(b.y)) << 16);
        unsigned int r3 = f2bf(rho_f(b.z)) | ((unsigned int)f2bf(rho_f(b.w)) << 16);
        uint4 o; o.x = r0; o.y = r1; o.z = r2; o.w = r3;
        ((uint4*)Rs)[i] = o;
    }
}

// ------- prep: Wb = bf16(W); WTb = transpose. Block (1,0) of W is never
// read by either GEMM's K-ranges -> skip it (mask input unused). -------
__global__ void prep_w_kernel(const float* __restrict__ W,
                              unsigned short* __restrict__ Wb,
                              unsigned short* __restrict__ WTb) {
    if (blockIdx.y * 32 >= D1_DIM && blockIdx.x * 32 < D1_DIM) return;  // dead
    __shared__ unsigned short t[32][33];
    int x = blockIdx.x * 32 + threadIdx.x;
    #pragma unroll
    for (int r = 0; r < 4; r++) {
        int y = blockIdx.y * 32 + threadIdx.y + r * 8;
        size_t idx = (size_t)y * N_DIM + x;
        unsigned short b = f2bf(W[idx]);
        Wb[idx] = b;
        t[threadIdx.y + r * 8][threadIdx.x] = b;
    }
    __syncthreads();
    #pragma unroll
    for (int r = 0; r < 4; r++) {
        int yy = threadIdx.y + r * 8;
        int orow = blockIdx.x * 32 + yy;
        int ocol = blockIdx.y * 32 + threadIdx.x;
        WTb[(size_t)orow * N_DIM + ocol] = t[threadIdx.x][yy];
    }
}

// ---------------- GEMM 256x256, BK=64, 8 waves, 4 phases/K-tile ----------
// C = A @ Bt^T. A[M][K], Bt[N][K] bf16 row-major (ld=4096), fp32 acc.
// LDS: A bufs a0/a1/a2 at 0/32K/64K (tile t uses a[t%3]); B bufs b0/b1 at
// 96K/128K (tile t uses b[t%2]). Stage A(t+2) at p1-p2 -> a[(t+2)%3],
// B(t+2) at p3-p4 -> b[t%2] (slots freed after p2). vmcnt(8) at p4 drains
// exactly tile t+1's 8 loads (FIFO), leaving t+2's 8 in flight.
// Swizzle: LDS[r][chunk c] = G[r][c ^ (r&7)], source-side + read-side.
template<int MODE>
__global__ __launch_bounds__(512, 2) void gemm_kernel(
    const unsigned short* __restrict__ A,
    const unsigned short* __restrict__ Bt,
    void* __restrict__ Out,
    const float* __restrict__ Ux,
    const float* __restrict__ bias) {
    __shared__ __align__(16) char lds[163840];

    // XCD remap: XCD x gets tile-rows {2x, 2x+1}
    const int id = blockIdx.x;
    const int wg = ((id & 7) << 5) | (id >> 3);
    const int by = wg >> 4, bx = wg & 15;
    const int brow = by << 8, bcol = bx << 8;

    const int tid = threadIdx.x;
    const int w = tid >> 6;
    const int L = tid & 63;
    const int wr = w >> 2;         // 0..1 : rows wr*128..+127
    const int wc = w & 3;          // 0..3 : cols wc*64..+63
    const int fr = L & 15;
    const int fq = L >> 4;
    const int swz = fr & 7;

    // block-sparse K range (exact: skipped W blocks are all-zero)
    int kbeg, kend;
    if (MODE == 1) { kbeg = 0; kend = (bcol < D1_DIM) ? D1_DIM : N_DIM; }
    else           { kbeg = (bcol < D1_DIM) ? 0 : D1_DIM; kend = N_DIM; }

    // staging: one round = 1 gl_lds16/thread = 64 rows x 64 cols (8KB)
    const int srl = w * 8 + (L >> 3);
    const int schunk8 = ((L & 7) ^ (L >> 3)) << 3;
    const int wbase = w * 1024;
    // STAGE2 = one half (128 rows x 64 cols, 2 rounds = 2 gl_lds16/thread)
#define STAGE2(mat, gb, h, kcol, base) do {                                    \
        const unsigned short* g0_ = (mat) +                                    \
            (size_t)((gb) + (h) * 128 + srl) * N_DIM + (kcol) + schunk8;       \
        gl_lds16(g0_, lds + (base) + (h) * 16384 + wbase);                     \
        gl_lds16(g0_ + 64 * N_DIM, lds + (base) + (h) * 16384 + 8192 + wbase); \
    } while (0)

    short8 af[2][4], bf0[2][2], bf1[2][2];
#define LDA_Q(ab, qm) do {                                                     \
        _Pragma("unroll") for (int s_ = 0; s_ < 2; ++s_)                       \
        _Pragma("unroll") for (int m_ = 0; m_ < 4; ++m_) {                     \
            const int R_ = wr * 128 + (qm) * 64 + m_ * 16 + fr;                \
            af[s_][m_] = *(const short8*)(lds + (ab) + R_ * 128 +              \
                (((4 * s_ + fq) ^ swz) << 4)); }                               \
    } while (0)
#define LDB_Q(bb, qn, dst) do {                                                \
        _Pragma("unroll") for (int s_ = 0; s_ < 2; ++s_)                       \
        _Pragma("unroll") for (int n_ = 0; n_ < 2; ++n_) {                     \
            const int R_ = wc * 64 + (qn) * 32 + n_ * 16 + fr;                 \
            dst[s_][n_] = *(const short8*)(lds + (bb) + R_ * 128 +             \
                (((4 * s_ + fq) ^ swz) << 4)); }                               \
    } while (0)

    f32x4 acc[8][4];
    #pragma unroll
    for (int i = 0; i < 8; i++)
        #pragma unroll
        for (int j = 0; j < 4; j++)
            acc[i][j] = (f32x4){0.f, 0.f, 0.f, 0.f};

#define MFMA_Q(qm, qn, bfr) do {                                               \
        __builtin_amdgcn_s_setprio(1);                                         \
        _Pragma("unroll") for (int s_ = 0; s_ < 2; ++s_)                       \
        _Pragma("unroll") for (int m_ = 0; m_ < 4; ++m_)                       \
        _Pragma("unroll") for (int n_ = 0; n_ < 2; ++n_)                       \
            acc[(qm) * 4 + m_][(qn) * 2 + n_] =                                \
                __builtin_amdgcn_mfma_f32_16x16x32_bf16(                       \
                    af[s_][m_], bfr[s_][n_], acc[(qm) * 4 + m_][(qn) * 2 + n_],\
                    0, 0, 0);                                                  \
        __builtin_amdgcn_s_setprio(0);                                         \
    } while (0)

#define LGKM0() do { asm volatile("s_waitcnt lgkmcnt(0)" ::: "memory");        \
                     __builtin_amdgcn_sched_barrier(0); } while (0)
#define BAR() __builtin_amdgcn_s_barrier()

    const int nk = (kend - kbeg) >> 6;   // 32 or 64
    const int km = nk - 1;

    // ---- prologue: A(0),B(0),A(1),B(1) (16 loads, FIFO order = need order)
    {
        const int k0 = kbeg;
        const int k1 = kbeg + ((1 & km) << 6);
        STAGE2(A, brow, 0, k0, 0);       STAGE2(A, brow, 1, k0, 0);
        STAGE2(Bt, bcol, 0, k0, 98304);  STAGE2(Bt, bcol, 1, k0, 98304);
        STAGE2(A, brow, 0, k1, 32768);   STAGE2(A, brow, 1, k1, 32768);
        STAGE2(Bt, bcol, 0, k1, 131072); STAGE2(Bt, bcol, 1, k1, 131072);
        asm volatile("s_waitcnt vmcnt(8)" ::: "memory");  // A(0),B(0) ready
        BAR();
    }

    int ai = 0, si = 2, bi = 0;          // a[t%3], a[(t+2)%3], b[t%2]
    for (int t = 0; t < nk; ++t) {
        const int aB = ai * 32768;
        const int sA = si * 32768;
        const int bB = 98304 + bi * 32768;
        const int ka = kbeg + (((t + 2) & km) << 6);   // wrapped tail: dead

        // p1: frags qm0 + bf0; stage A(t+2)h0 -> a[(t+2)%3]
        LDA_Q(aB, 0); LDB_Q(bB, 0, bf0);
        STAGE2(A, brow, 0, ka, sA);
        BAR(); LGKM0();
        MFMA_Q(0, 0, bf0);
        BAR();

        // p2: bf1; stage A(t+2)h1
        LDB_Q(bB, 1, bf1);
        STAGE2(A, brow, 1, ka, sA);
        BAR(); LGKM0();
        MFMA_Q(0, 1, bf1);
        BAR();

        // p3: frags qm1; stage B(t+2)h0 -> b[t%2] (B(t) reads drained at p2)
        LDA_Q(aB, 1);
        STAGE2(Bt, bcol, 0, ka, bB);
        BAR(); LGKM0();
        MFMA_Q(1, 1, bf1);
        BAR();

        // p4: stage B(t+2)h1; vmcnt(8) drains exactly tile t+1 (FIFO),
        // leaving A(t+2)+B(t+2)'s 8 loads in flight
        STAGE2(Bt, bcol, 1, ka, bB);
        asm volatile("s_waitcnt vmcnt(8)" ::: "memory");
        BAR();
        __builtin_amdgcn_sched_barrier(0);
        MFMA_Q(1, 0, bf0);
        BAR();

        ai++; if (ai == 3) ai = 0;
        si++; if (si == 3) si = 0;
        bi ^= 1;
    }
    // drain dead tail stages: must not land in the NEXT block's LDS
    asm volatile("s_waitcnt vmcnt(0)" ::: "memory");

    // ---- epilogue: C/D layout col = fr (N), row = fq*4 + reg (M) ----
    const bool hasUx = (MODE == 1) && (bcol < D1_DIM);
    #pragma unroll
    for (int qm = 0; qm < 2; qm++)
        #pragma unroll
        for (int m = 0; m < 4; m++) {
            const int row0 = brow + wr * 128 + qm * 64 + m * 16 + fq * 4;
            #pragma unroll
            for (int qn = 0; qn < 2; qn++)
                #pragma unroll
                for (int n = 0; n < 2; n++) {
                    const int col = bcol + wc * 64 + qn * 32 + n * 16 + fr;
                    const float bv = bias[col];
                    #pragma unroll
                    for (int r = 0; r < 4; r++) {
                        const int row = row0 + r;
                        float v = acc[qm * 4 + m][qn * 2 + n][r] + bv;
                        if (MODE == 1) {
                            if (hasUx) v += Ux[(size_t)row * D1_DIM + col];
                            ((unsigned short*)Out)[(size_t)row * N_DIM + col] =
                                f2bf(rho_f(v));
                        } else {
                            ((float*)Out)[(size_t)row * N_DIM + col] = v;
                        }
                    }
                }
        }
#undef STAGE2
#undef LDA_Q
#undef LDB_Q
#undef MFMA_Q
#undef LGKM0
#undef BAR
}

extern "C" void kernel_launch(void* const* d_in, const int* in_sizes, int n_in,
                              void* d_out, int out_size, void* d_ws, size_t ws_size,
                              hipStream_t stream) {
    const float* Ux     = (const float*)d_in[0];  // [4096][2048]
    const float* s      = (const float*)d_in[1];  // [4096][4096]
    const float* W      = (const float*)d_in[2];  // [4096][4096]
    const float* b_even = (const float*)d_in[3];  // [4096]
    const float* b_odd  = (const float*)d_in[4];  // [4096]
    // d_in[5] = W_mask: unused (masked block is never read)

    char* ws = (char*)d_ws;
    const size_t SZ = (size_t)N_DIM * N_DIM * 2;  // 32 MB per bf16 matrix
    unsigned short* Rs  = (unsigned short*)(ws);
    unsigned short* R2  = (unsigned short*)(ws + SZ);
    unsigned short* Wb  = (unsigned short*)(ws + 2 * SZ);
    unsigned short* WTb = (unsigned short*)(ws + 3 * SZ);

    prep_rs_kernel<<<2048, 256, 0, stream>>>(s, Rs, (N_DIM * N_DIM) / 8);
    prep_w_kernel<<<dim3(128, 128), dim3(32, 8), 0, stream>>>(W, Wb, WTb);
    // GEMM1: s_odd = Rs @ W  (+b_odd, +Ux, rho) -> R2 bf16
    gemm_kernel<1><<<256, 512, 0, stream>>>(Rs, WTb, (void*)R2, Ux, b_odd);
    // GEMM2: out = R2 @ W^T (+b_even) -> d_out f32
    gemm_kernel<2><<<256, 512, 0, stream>>>(R2, Wb, d_out, Ux, b_even);
}

// Round 6
// 266.345 us; speedup vs baseline: 1.8313x; 1.0283x over previous
//
#include <hip/hip_runtime.h>
#include <hip/hip_bf16.h>

// EvenOddFunctionHAM: out = rho(rho(s)@W + b_odd + [Ux|0]) @ W^T + b_even
// R5 -> R6: barrier-count surgery. Keep R5's 256x256/8-wave geometry and
// 3xA + 2xB LDS buffering, but replace {4 phases x 2 barriers, lgkmcnt(0)
// per phase} with {2 barriers/K-tile + counted lgkmcnt}: issue all 24
// ds_reads up front in pinned order [A0,B0,B1,A1], consume with
// lgkmcnt(12)/(8)/(0) so LDS drain overlaps MFMA. vmcnt(8) once per tile.

#define N_DIM 4096
#define D1_DIM 2048

typedef short short8 __attribute__((ext_vector_type(8)));
typedef float f32x4 __attribute__((ext_vector_type(4)));

__device__ __forceinline__ float rho_f(float x) {
    return 1.0f / (1.0f + __expf(2.0f - 4.0f * x));  // sigmoid(4x-2)
}

__device__ __forceinline__ unsigned short f2bf(float x) {
    unsigned int u = __builtin_bit_cast(unsigned int, x);
    u += 0x7fffu + ((u >> 16) & 1u);
    return (unsigned short)(u >> 16);
}

__device__ __forceinline__ void gl_lds16(const unsigned short* g, void* l) {
    __builtin_amdgcn_global_load_lds(
        (const __attribute__((address_space(1))) void*)g,
        (__attribute__((address_space(3))) void*)l, 16, 0, 0);
}

// ---------------- prep: Rs = bf16(rho(s)) ----------------
__global__ void prep_rs_kernel(const float* __restrict__ s,
                               unsigned short* __restrict__ Rs, int n8) {
    int t = blockIdx.x * blockDim.x + threadIdx.x;
    int stride = gridDim.x * blockDim.x;
    for (int i = t; i < n8; i += stride) {
        float4 a = ((const float4*)s)[2 * i];
        float4 b = ((const float4*)s)[2 * i + 1];
        unsigned int r0 = f2bf(rho_f(a.x)) | ((unsigned int)f2bf(rho_f(a.y)) << 16);
        unsigned int r1 = f2bf(rho_f(a.z)) | ((unsigned int)f2bf(rho_f(a.w)) << 16);
        unsigned int r2 = f2bf(rho_f(b.x)) | ((unsigned int)f2bf(rho_f(b.y)) << 16);
        unsigned int r3 = f2bf(rho_f(b.z)) | ((unsigned int)f2bf(rho_f(b.w)) << 16);
        uint4 o; o.x = r0; o.y = r1; o.z = r2; o.w = r3;
        ((uint4*)Rs)[i] = o;
    }
}

// ------- prep: Wb = bf16(W); WTb = transpose. Block (1,0) of W is never
// read by either GEMM's K-ranges -> skip it (mask input unused). -------
__global__ void prep_w_kernel(const float* __restrict__ W,
                              unsigned short* __restrict__ Wb,
                              unsigned short* __restrict__ WTb) {
    if (blockIdx.y * 32 >= D1_DIM && blockIdx.x * 32 < D1_DIM) return;  // dead
    __shared__ unsigned short t[32][33];
    int x = blockIdx.x * 32 + threadIdx.x;
    #pragma unroll
    for (int r = 0; r < 4; r++) {
        int y = blockIdx.y * 32 + threadIdx.y + r * 8;
        size_t idx = (size_t)y * N_DIM + x;
        unsigned short b = f2bf(W[idx]);
        Wb[idx] = b;
        t[threadIdx.y + r * 8][threadIdx.x] = b;
    }
    __syncthreads();
    #pragma unroll
    for (int r = 0; r < 4; r++) {
        int yy = threadIdx.y + r * 8;
        int orow = blockIdx.x * 32 + yy;
        int ocol = blockIdx.y * 32 + threadIdx.x;
        WTb[(size_t)orow * N_DIM + ocol] = t[threadIdx.x][yy];
    }
}

// ---------------- GEMM 256x256, BK=64, 8 waves, 2 barriers/K-tile --------
// C = A @ Bt^T. A[M][K], Bt[N][K] bf16 row-major (ld=4096), fp32 acc.
// LDS: A bufs at 0/32K/64K (tile t reads a[t%3], stages A(t+2)->a[(t+2)%3]);
// B bufs at 96K/128K (tile t reads b[t%2], stages B(t+2)->b[t%2] after
// BAR#1). ds_reads issued up front [A0,B0,B1,A1], consumed via counted
// lgkmcnt. vmcnt(8) at tile end drains exactly tile t+1 (FIFO).
// Swizzle: LDS[r][chunk c] = G[r][c ^ (r&7)], source-side + read-side.
template<int MODE>
__global__ __launch_bounds__(512, 2) void gemm_kernel(
    const unsigned short* __restrict__ A,
    const unsigned short* __restrict__ Bt,
    void* __restrict__ Out,
    const float* __restrict__ Ux,
    const float* __restrict__ bias) {
    __shared__ __align__(16) char lds[163840];

    // XCD remap: XCD x gets tile-rows {2x, 2x+1}
    const int id = blockIdx.x;
    const int wg = ((id & 7) << 5) | (id >> 3);
    const int by = wg >> 4, bx = wg & 15;
    const int brow = by << 8, bcol = bx << 8;

    const int tid = threadIdx.x;
    const int w = tid >> 6;
    const int L = tid & 63;
    const int wr = w >> 2;         // 0..1 : rows wr*128..+127
    const int wc = w & 3;          // 0..3 : cols wc*64..+63
    const int fr = L & 15;
    const int fq = L >> 4;
    const int swz = fr & 7;

    // block-sparse K range (exact: skipped W blocks are all-zero)
    int kbeg, kend;
    if (MODE == 1) { kbeg = 0; kend = (bcol < D1_DIM) ? D1_DIM : N_DIM; }
    else           { kbeg = (bcol < D1_DIM) ? 0 : D1_DIM; kend = N_DIM; }

    // staging: one round = 1 gl_lds16/thread = 64 rows x 64 cols (8KB)
    const int srl = w * 8 + (L >> 3);
    const int schunk8 = ((L & 7) ^ (L >> 3)) << 3;
    const int wbase = w * 1024;
#define STAGE2(mat, gb, h, kcol, base) do {                                    \
        const unsigned short* g0_ = (mat) +                                    \
            (size_t)((gb) + (h) * 128 + srl) * N_DIM + (kcol) + schunk8;       \
        gl_lds16(g0_, lds + (base) + (h) * 16384 + wbase);                     \
        gl_lds16(g0_ + 64 * N_DIM, lds + (base) + (h) * 16384 + 8192 + wbase); \
    } while (0)

    short8 af0[2][4], af1[2][4], bf0[2][2], bf1[2][2];
#define LDA_Q(ab, qm, dst) do {                                                \
        _Pragma("unroll") for (int s_ = 0; s_ < 2; ++s_)                       \
        _Pragma("unroll") for (int m_ = 0; m_ < 4; ++m_) {                     \
            const int R_ = wr * 128 + (qm) * 64 + m_ * 16 + fr;                \
            dst[s_][m_] = *(const short8*)(lds + (ab) + R_ * 128 +             \
                (((4 * s_ + fq) ^ swz) << 4)); }                               \
    } while (0)
#define LDB_Q(bb, qn, dst) do {                                                \
        _Pragma("unroll") for (int s_ = 0; s_ < 2; ++s_)                       \
        _Pragma("unroll") for (int n_ = 0; n_ < 2; ++n_) {                     \
            const int R_ = wc * 64 + (qn) * 32 + n_ * 16 + fr;                 \
            dst[s_][n_] = *(const short8*)(lds + (bb) + R_ * 128 +             \
                (((4 * s_ + fq) ^ swz) << 4)); }                               \
    } while (0)

    f32x4 acc[8][4];
    #pragma unroll
    for (int i = 0; i < 8; i++)
        #pragma unroll
        for (int j = 0; j < 4; j++)
            acc[i][j] = (f32x4){0.f, 0.f, 0.f, 0.f};

#define MFMA_Q(afr, bfr, qm, qn) do {                                          \
        __builtin_amdgcn_s_setprio(1);                                         \
        _Pragma("unroll") for (int s_ = 0; s_ < 2; ++s_)                       \
        _Pragma("unroll") for (int m_ = 0; m_ < 4; ++m_)                       \
        _Pragma("unroll") for (int n_ = 0; n_ < 2; ++n_)                       \
            acc[(qm) * 4 + m_][(qn) * 2 + n_] =                                \
                __builtin_amdgcn_mfma_f32_16x16x32_bf16(                       \
                    afr[s_][m_], bfr[s_][n_], acc[(qm) * 4 + m_][(qn) * 2 + n_],\
                    0, 0, 0);                                                  \
        __builtin_amdgcn_s_setprio(0);                                         \
    } while (0)

#define SBAR0() __builtin_amdgcn_sched_barrier(0)
#define LGKM(n) do { asm volatile("s_waitcnt lgkmcnt(" #n ")" ::: "memory");   \
                     SBAR0(); } while (0)
#define BAR() __builtin_amdgcn_s_barrier()

    const int nk = (kend - kbeg) >> 6;   // 32 or 64
    const int km = nk - 1;

    // ---- prologue: A(0),B(0),A(1),B(1) (16 loads, FIFO); t0 ready
    {
        const int k0 = kbeg;
        const int k1 = kbeg + ((1 & km) << 6);
        STAGE2(A, brow, 0, k0, 0);       STAGE2(A, brow, 1, k0, 0);
        STAGE2(Bt, bcol, 0, k0, 98304);  STAGE2(Bt, bcol, 1, k0, 98304);
        STAGE2(A, brow, 0, k1, 32768);   STAGE2(A, brow, 1, k1, 32768);
        STAGE2(Bt, bcol, 0, k1, 131072); STAGE2(Bt, bcol, 1, k1, 131072);
        asm volatile("s_waitcnt vmcnt(8)" ::: "memory");  // A(0),B(0) ready
        BAR();
    }

    int ai = 0, si = 2;                   // a[t%3], a[(t+2)%3]
    for (int t = 0; t < nk; ++t) {
        const int aB = ai * 32768;
        const int sA = si * 32768;
        const int bB = 98304 + (t & 1) * 32768;
        const int ka = kbeg + (((t + 2) & km) << 6);   // wrapped tail: dead

        // issue all 24 ds_reads, pinned order: A0(8), B0(4), B1(4), A1(8)
        LDA_Q(aB, 0, af0); SBAR0();
        LDB_Q(bB, 0, bf0); SBAR0();
        LDB_Q(bB, 1, bf1); SBAR0();
        LDA_Q(aB, 1, af1); SBAR0();
        // stage A(t+2) -> a[(t+2)%3] (read iter t-1; safe after its tile-end BAR)
        STAGE2(A, brow, 0, ka, sA);
        STAGE2(A, brow, 1, ka, sA);

        LGKM(12);                      // A0+B0 landed
        MFMA_Q(af0, bf0, 0, 0);
        LGKM(8);                       // +B1 landed (all B reads done)
        MFMA_Q(af0, bf1, 0, 1);
        BAR();                         // #1: all waves' B reads done
        // stage B(t+2) -> b[t%2] (slot just freed)
        STAGE2(Bt, bcol, 0, ka, bB);
        STAGE2(Bt, bcol, 1, ka, bB);
        LGKM(0);                       // +A1 landed
        MFMA_Q(af1, bf0, 1, 0);
        MFMA_Q(af1, bf1, 1, 1);
        // drain exactly tile t+1's 8 loads (FIFO), keep t+2's 8 in flight
        asm volatile("s_waitcnt vmcnt(8)" ::: "memory");
        BAR();                         // #2: tile boundary
        ai++; if (ai == 3) ai = 0;
        si++; if (si == 3) si = 0;
    }
    // drain dead tail stages: must not land in the NEXT block's LDS
    asm volatile("s_waitcnt vmcnt(0)" ::: "memory");

    // ---- epilogue: C/D layout col = fr (N), row = fq*4 + reg (M) ----
    const bool hasUx = (MODE == 1) && (bcol < D1_DIM);
    #pragma unroll
    for (int qm = 0; qm < 2; qm++)
        #pragma unroll
        for (int m = 0; m < 4; m++) {
            const int row0 = brow + wr * 128 + qm * 64 + m * 16 + fq * 4;
            #pragma unroll
            for (int qn = 0; qn < 2; qn++)
                #pragma unroll
                for (int n = 0; n < 2; n++) {
                    const int col = bcol + wc * 64 + qn * 32 + n * 16 + fr;
                    const float bv = bias[col];
                    #pragma unroll
                    for (int r = 0; r < 4; r++) {
                        const int row = row0 + r;
                        float v = acc[qm * 4 + m][qn * 2 + n][r] + bv;
                        if (MODE == 1) {
                            if (hasUx) v += Ux[(size_t)row * D1_DIM + col];
                            ((unsigned short*)Out)[(size_t)row * N_DIM + col] =
                                f2bf(rho_f(v));
                        } else {
                            ((float*)Out)[(size_t)row * N_DIM + col] = v;
                        }
                    }
                }
        }
#undef STAGE2
#undef LDA_Q
#undef LDB_Q
#undef MFMA_Q
#undef SBAR0
#undef LGKM
#undef BAR
}

extern "C" void kernel_launch(void* const* d_in, const int* in_sizes, int n_in,
                              void* d_out, int out_size, void* d_ws, size_t ws_size,
                              hipStream_t stream) {
    const float* Ux     = (const float*)d_in[0];  // [4096][2048]
    const float* s      = (const float*)d_in[1];  // [4096][4096]
    const float* W      = (const float*)d_in[2];  // [4096][4096]
    const float* b_even = (const float*)d_in[3];  // [4096]
    const float* b_odd  = (const float*)d_in[4];  // [4096]
    // d_in[5] = W_mask: unused (masked block is never read)

    char* ws = (char*)d_ws;
    const size_t SZ = (size_t)N_DIM * N_DIM * 2;  // 32 MB per bf16 matrix
    unsigned short* Rs  = (unsigned short*)(ws);
    unsigned short* R2  = (unsigned short*)(ws + SZ);
    unsigned short* Wb  = (unsigned short*)(ws + 2 * SZ);
    unsigned short* WTb = (unsigned short*)(ws + 3 * SZ);

    prep_rs_kernel<<<2048, 256, 0, stream>>>(s, Rs, (N_DIM * N_DIM) / 8);
    prep_w_kernel<<<dim3(128, 128), dim3(32, 8), 0, stream>>>(W, Wb, WTb);
    // GEMM1: s_odd = Rs @ W  (+b_odd, +Ux, rho) -> R2 bf16
    gemm_kernel<1><<<256, 512, 0, stream>>>(Rs, WTb, (void*)R2, Ux, b_odd);
    // GEMM2: out = R2 @ W^T (+b_even) -> d_out f32
    gemm_kernel<2><<<256, 512, 0, stream>>>(R2, Wb, d_out, Ux, b_even);
}